// Round 1
// baseline (884.257 us; speedup 1.0000x reference)
//
#include <hip/hip_runtime.h>
#include <hip/hip_bf16.h>

// Problem constants
#define BB 2
#define TT 2048
#define CC 512
#define HH 8
#define HD 64
#define NR 4096   // B*T rows

// ---------------------------------------------------------------------------
// conv_w [O=512][I=512][K=3]  ->  wT [k][i][o]  (coalesced B-operand tiles)
// ---------------------------------------------------------------------------
__global__ void transpose_w_kernel(const float* __restrict__ w, float* __restrict__ wT) {
    int idx = blockIdx.x * 256 + threadIdx.x;
    if (idx >= 3 * CC * CC) return;
    int o = idx & 511;
    int i = (idx >> 9) & 511;
    int k = idx >> 18;
    wT[idx] = w[(o * CC + i) * 3 + k];
}

// ---------------------------------------------------------------------------
// Row LayerNorm over C=512: one block per row, 256 threads, 2 elems/thread
// ---------------------------------------------------------------------------
__global__ __launch_bounds__(256) void ln_kernel(const float* __restrict__ in,
                                                 const float* __restrict__ g,
                                                 const float* __restrict__ b,
                                                 float* __restrict__ out) {
    int row = blockIdx.x;
    int tid = threadIdx.x;
    const float* p = in + (size_t)row * CC;
    float2 v = *(const float2*)(p + tid * 2);
    float s = v.x + v.y;
    float ss = v.x * v.x + v.y * v.y;
    #pragma unroll
    for (int off = 1; off < 64; off <<= 1) {
        s  += __shfl_xor(s, off);
        ss += __shfl_xor(ss, off);
    }
    __shared__ float sm[4], sm2[4];
    int w = tid >> 6;
    if ((tid & 63) == 0) { sm[w] = s; sm2[w] = ss; }
    __syncthreads();
    s  = sm[0] + sm[1] + sm[2] + sm[3];
    ss = sm2[0] + sm2[1] + sm2[2] + sm2[3];
    float mean = s * (1.f / CC);
    float var  = ss * (1.f / CC) - mean * mean;
    float rstd = rsqrtf(var + 1e-5f);
    float2 gg = *(const float2*)(g + tid * 2);
    float2 bb = *(const float2*)(b + tid * 2);
    float2 o;
    o.x = (v.x - mean) * rstd * gg.x + bb.x;
    o.y = (v.y - mean) * rstd * gg.y + bb.y;
    *(float2*)(out + (size_t)row * CC + tid * 2) = o;
}

// ---------------------------------------------------------------------------
// f32 tiled GEMM: C[M=4096,N] = A[4096,K] @ B[K,N] (+bias) (+res) (ReLU?)
// 128x128 tile, BK=16, 256 threads, 8x8 microtile. N,K multiples of 128/16.
// ---------------------------------------------------------------------------
template<bool RELU, bool RES>
__global__ __launch_bounds__(256) void gemm128(const float* __restrict__ A,
                                               const float* __restrict__ B,
                                               const float* __restrict__ bias,
                                               const float* __restrict__ res,
                                               float* __restrict__ C,
                                               int N, int K) {
    __shared__ float As[16][132];   // transposed A tile [k][row], padded
    __shared__ float Bs[16][128];
    int tid = threadIdx.x;
    int tx = tid & 15, ty = tid >> 4;
    int n0 = blockIdx.x * 128, m0 = blockIdx.y * 128;
    float acc[8][8];
    #pragma unroll
    for (int i = 0; i < 8; i++)
        #pragma unroll
        for (int j = 0; j < 8; j++) acc[i][j] = 0.f;

    for (int k0 = 0; k0 < K; k0 += 16) {
        #pragma unroll
        for (int l = 0; l < 2; l++) {
            int f = tid + l * 256;
            int row = f >> 2, k4 = (f & 3) << 2;
            float4 a = *(const float4*)(A + (size_t)(m0 + row) * K + k0 + k4);
            As[k4 + 0][row] = a.x; As[k4 + 1][row] = a.y;
            As[k4 + 2][row] = a.z; As[k4 + 3][row] = a.w;
        }
        #pragma unroll
        for (int l = 0; l < 2; l++) {
            int f = tid + l * 256;
            int kr = f >> 5, c4 = (f & 31) << 2;
            *(float4*)&Bs[kr][c4] = *(const float4*)(B + (size_t)(k0 + kr) * N + n0 + c4);
        }
        __syncthreads();
        #pragma unroll
        for (int kk = 0; kk < 16; kk++) {
            float a[8], bv[8];
            *(float4*)&a[0]  = *(const float4*)&As[kk][ty * 8];
            *(float4*)&a[4]  = *(const float4*)&As[kk][ty * 8 + 4];
            *(float4*)&bv[0] = *(const float4*)&Bs[kk][tx * 8];
            *(float4*)&bv[4] = *(const float4*)&Bs[kk][tx * 8 + 4];
            #pragma unroll
            for (int i = 0; i < 8; i++)
                #pragma unroll
                for (int j = 0; j < 8; j++)
                    acc[i][j] += a[i] * bv[j];
        }
        __syncthreads();
    }
    #pragma unroll
    for (int i = 0; i < 8; i++) {
        int row = m0 + ty * 8 + i;
        #pragma unroll
        for (int j = 0; j < 8; j += 4) {
            int col = n0 + tx * 8 + j;
            float4 v = make_float4(acc[i][j], acc[i][j+1], acc[i][j+2], acc[i][j+3]);
            float4 bb = *(const float4*)(bias + col);
            v.x += bb.x; v.y += bb.y; v.z += bb.z; v.w += bb.w;
            if (RES) {
                float4 r = *(const float4*)(res + (size_t)row * N + col);
                v.x += r.x; v.y += r.y; v.z += r.z; v.w += r.w;
            }
            if (RELU) {
                v.x = fmaxf(v.x, 0.f); v.y = fmaxf(v.y, 0.f);
                v.z = fmaxf(v.z, 0.f); v.w = fmaxf(v.w, 0.f);
            }
            *(float4*)(C + (size_t)row * N + col) = v;
        }
    }
}

// ---------------------------------------------------------------------------
// Causal dilated conv as 3-tap shifted GEMM, fused +bias +residual(x)
// y[r,o] = sum_tap sum_i x[r+tap-2, i] * wT[tap][i][o] + cb[o] + x[r,o]
// ---------------------------------------------------------------------------
__global__ __launch_bounds__(256) void conv_gemm(const float* __restrict__ x,
                                                 const float* __restrict__ wT,
                                                 const float* __restrict__ cb,
                                                 float* __restrict__ y) {
    __shared__ float As[16][132];
    __shared__ float Bs[16][128];
    int tid = threadIdx.x;
    int tx = tid & 15, ty = tid >> 4;
    int n0 = blockIdx.x * 128, m0 = blockIdx.y * 128;
    float acc[8][8];
    #pragma unroll
    for (int i = 0; i < 8; i++)
        #pragma unroll
        for (int j = 0; j < 8; j++) acc[i][j] = 0.f;

    for (int tap = 0; tap < 3; tap++) {
        int shift = tap - 2;
        for (int k0 = 0; k0 < CC; k0 += 16) {
            #pragma unroll
            for (int l = 0; l < 2; l++) {
                int f = tid + l * 256;
                int row = f >> 2, k4 = (f & 3) << 2;
                int r = m0 + row;
                int t = r & (TT - 1);
                bool ok = (t + shift) >= 0;
                float4 a = make_float4(0.f, 0.f, 0.f, 0.f);
                if (ok) a = *(const float4*)(x + (size_t)(r + shift) * CC + k0 + k4);
                As[k4 + 0][row] = a.x; As[k4 + 1][row] = a.y;
                As[k4 + 2][row] = a.z; As[k4 + 3][row] = a.w;
            }
            #pragma unroll
            for (int l = 0; l < 2; l++) {
                int f = tid + l * 256;
                int kr = f >> 5, c4 = (f & 31) << 2;
                *(float4*)&Bs[kr][c4] =
                    *(const float4*)(wT + (size_t)(tap * CC + k0 + kr) * CC + n0 + c4);
            }
            __syncthreads();
            #pragma unroll
            for (int kk = 0; kk < 16; kk++) {
                float a[8], bv[8];
                *(float4*)&a[0]  = *(const float4*)&As[kk][ty * 8];
                *(float4*)&a[4]  = *(const float4*)&As[kk][ty * 8 + 4];
                *(float4*)&bv[0] = *(const float4*)&Bs[kk][tx * 8];
                *(float4*)&bv[4] = *(const float4*)&Bs[kk][tx * 8 + 4];
                #pragma unroll
                for (int i = 0; i < 8; i++)
                    #pragma unroll
                    for (int j = 0; j < 8; j++)
                        acc[i][j] += a[i] * bv[j];
            }
            __syncthreads();
        }
    }
    #pragma unroll
    for (int i = 0; i < 8; i++) {
        int row = m0 + ty * 8 + i;
        #pragma unroll
        for (int j = 0; j < 8; j += 4) {
            int col = n0 + tx * 8 + j;
            float4 v = make_float4(acc[i][j], acc[i][j+1], acc[i][j+2], acc[i][j+3]);
            float4 bb = *(const float4*)(cb + col);
            float4 r  = *(const float4*)(x + (size_t)row * CC + col);
            v.x += bb.x + r.x; v.y += bb.y + r.y;
            v.z += bb.z + r.z; v.w += bb.w + r.w;
            *(float4*)(y + (size_t)row * CC + col) = v;
        }
    }
}

// ---------------------------------------------------------------------------
// Flash-style causal attention, f32. qkv [4096][1536] (q|k|v each 512).
// grid: (qt=32, bh=16). block 256 = 16x16, 4x4 microtile of the 64x64 S tile.
// ---------------------------------------------------------------------------
__global__ __launch_bounds__(256) void attn_kernel(const float* __restrict__ qkv,
                                                   float* __restrict__ outp) {
    __shared__ float Qs[64][68];   // transposed [d][r]
    __shared__ float KVs[64][68];  // K transposed [d][c], then V direct [c][d]
    __shared__ float Ps[64][68];   // P [r][c]
    int tid = threadIdx.x;
    int tx = tid & 15, ty = tid >> 4;
    int qt = blockIdx.x;
    int bh = blockIdx.y;
    int b = bh >> 3, h = bh & 7;
    size_t base = (size_t)b * TT;
    int q0 = qt * 64;

    #pragma unroll
    for (int l = 0; l < 4; l++) {
        int f = tid + l * 256;
        int r = f >> 4, d4 = (f & 15) << 2;
        float4 v = *(const float4*)(qkv + (base + q0 + r) * 1536 + h * 64 + d4);
        Qs[d4 + 0][r] = v.x; Qs[d4 + 1][r] = v.y;
        Qs[d4 + 2][r] = v.z; Qs[d4 + 3][r] = v.w;
    }
    float mrow[4], lrow[4], acc[4][4];
    #pragma unroll
    for (int i = 0; i < 4; i++) {
        mrow[i] = -1e30f; lrow[i] = 0.f;
        #pragma unroll
        for (int j = 0; j < 4; j++) acc[i][j] = 0.f;
    }

    for (int kt = 0; kt <= qt; kt++) {
        __syncthreads();  // previous PV done (and Q stores on first iter)
        #pragma unroll
        for (int l = 0; l < 4; l++) {
            int f = tid + l * 256;
            int r = f >> 4, d4 = (f & 15) << 2;
            float4 v = *(const float4*)(qkv + (base + kt * 64 + r) * 1536 + 512 + h * 64 + d4);
            KVs[d4 + 0][r] = v.x; KVs[d4 + 1][r] = v.y;
            KVs[d4 + 2][r] = v.z; KVs[d4 + 3][r] = v.w;
        }
        __syncthreads();
        float s[4][4];
        #pragma unroll
        for (int i = 0; i < 4; i++)
            #pragma unroll
            for (int j = 0; j < 4; j++) s[i][j] = 0.f;
        #pragma unroll 16
        for (int kk = 0; kk < 64; kk++) {
            float4 a  = *(const float4*)&Qs[kk][ty * 4];
            float4 bv = *(const float4*)&KVs[kk][tx * 4];
            s[0][0] += a.x * bv.x; s[0][1] += a.x * bv.y; s[0][2] += a.x * bv.z; s[0][3] += a.x * bv.w;
            s[1][0] += a.y * bv.x; s[1][1] += a.y * bv.y; s[1][2] += a.y * bv.z; s[1][3] += a.y * bv.w;
            s[2][0] += a.z * bv.x; s[2][1] += a.z * bv.y; s[2][2] += a.z * bv.z; s[2][3] += a.z * bv.w;
            s[3][0] += a.w * bv.x; s[3][1] += a.w * bv.y; s[3][2] += a.w * bv.z; s[3][3] += a.w * bv.w;
        }
        __syncthreads();  // K reads done; safe to overwrite KVs with V
        #pragma unroll
        for (int l = 0; l < 4; l++) {
            int f = tid + l * 256;
            int r = f >> 4, d4 = (f & 15) << 2;
            *(float4*)&KVs[r][d4] =
                *(const float4*)(qkv + (base + kt * 64 + r) * 1536 + 1024 + h * 64 + d4);
        }
        const float sc = 0.125f;  // 1/sqrt(64)
        #pragma unroll
        for (int i = 0; i < 4; i++) {
            float rm = -1e30f;
            #pragma unroll
            for (int j = 0; j < 4; j++) {
                float v = s[i][j] * sc;
                if (kt == qt && (tx * 4 + j) > (ty * 4 + i)) v = -1e30f;
                s[i][j] = v;
                rm = fmaxf(rm, v);
            }
            rm = fmaxf(rm, __shfl_xor(rm, 1));
            rm = fmaxf(rm, __shfl_xor(rm, 2));
            rm = fmaxf(rm, __shfl_xor(rm, 4));
            rm = fmaxf(rm, __shfl_xor(rm, 8));
            float mn = fmaxf(mrow[i], rm);
            float alpha = __expf(mrow[i] - mn);
            mrow[i] = mn;
            float p0 = __expf(s[i][0] - mn);
            float p1 = __expf(s[i][1] - mn);
            float p2 = __expf(s[i][2] - mn);
            float p3 = __expf(s[i][3] - mn);
            float rs = p0 + p1 + p2 + p3;
            rs += __shfl_xor(rs, 1);
            rs += __shfl_xor(rs, 2);
            rs += __shfl_xor(rs, 4);
            rs += __shfl_xor(rs, 8);
            lrow[i] = lrow[i] * alpha + rs;
            #pragma unroll
            for (int j = 0; j < 4; j++) acc[i][j] *= alpha;
            *(float4*)&Ps[ty * 4 + i][tx * 4] = make_float4(p0, p1, p2, p3);
        }
        __syncthreads();  // V + P visible
        #pragma unroll 8
        for (int c = 0; c < 64; c++) {
            float4 bv = *(const float4*)&KVs[c][tx * 4];
            #pragma unroll
            for (int i = 0; i < 4; i++) {
                float pv = Ps[ty * 4 + i][c];
                acc[i][0] += pv * bv.x; acc[i][1] += pv * bv.y;
                acc[i][2] += pv * bv.z; acc[i][3] += pv * bv.w;
            }
        }
    }
    #pragma unroll
    for (int i = 0; i < 4; i++) {
        float inv = 1.f / lrow[i];
        float4 o = make_float4(acc[i][0] * inv, acc[i][1] * inv,
                               acc[i][2] * inv, acc[i][3] * inv);
        *(float4*)(outp + (base + q0 + ty * 4 + i) * CC + h * 64 + tx * 4) = o;
    }
}

// ---------------------------------------------------------------------------
extern "C" void kernel_launch(void* const* d_in, const int* in_sizes, int n_in,
                              void* d_out, int out_size, void* d_ws, size_t ws_size,
                              hipStream_t stream) {
    const float* x      = (const float*)d_in[0];
    const float* conv_w = (const float*)d_in[1];
    const float* conv_b = (const float*)d_in[2];
    const float* g1     = (const float*)d_in[3];
    const float* b1     = (const float*)d_in[4];
    const float* qkv_w  = (const float*)d_in[5];
    const float* qkv_b  = (const float*)d_in[6];
    const float* proj_w = (const float*)d_in[7];
    const float* proj_b = (const float*)d_in[8];
    const float* g2     = (const float*)d_in[9];
    const float* b2     = (const float*)d_in[10];
    const float* ffn_w1 = (const float*)d_in[11];
    const float* ffn_b1 = (const float*)d_in[12];
    const float* ffn_w2 = (const float*)d_in[13];
    const float* ffn_b2 = (const float*)d_in[14];
    const float* g3     = (const float*)d_in[15];
    const float* b3     = (const float*)d_in[16];
    float* out = (float*)d_out;

    float* wT      = (float*)d_ws;            // 786432
    float* buf     = wT + 786432;             // 2M (y1/y2/y3, reused)
    float* x1      = buf + 2097152;           // 2M
    float* x2      = x1 + 2097152;            // 2M
    float* attnout = x2 + 2097152;            // 2M
    float* qkvbuf  = attnout + 2097152;       // 6M
    float* hbuf    = qkvbuf;                  // 4M, aliases qkv (dead by then)

    transpose_w_kernel<<<3072, 256, 0, stream>>>(conv_w, wT);
    conv_gemm<<<dim3(4, 32), 256, 0, stream>>>(x, wT, conv_b, buf);
    ln_kernel<<<NR, 256, 0, stream>>>(buf, g1, b1, x1);
    gemm128<false, false><<<dim3(12, 32), 256, 0, stream>>>(x1, qkv_w, qkv_b, nullptr, qkvbuf, 1536, 512);
    attn_kernel<<<dim3(32, 16), 256, 0, stream>>>(qkvbuf, attnout);
    gemm128<false, true><<<dim3(4, 32), 256, 0, stream>>>(attnout, proj_w, proj_b, x1, buf, 512, 512);
    ln_kernel<<<NR, 256, 0, stream>>>(buf, g2, b2, x2);
    gemm128<true, false><<<dim3(8, 32), 256, 0, stream>>>(x2, ffn_w1, ffn_b1, nullptr, hbuf, 1024, 512);
    gemm128<false, true><<<dim3(4, 32), 256, 0, stream>>>(hbuf, ffn_w2, ffn_b2, x2, buf, 512, 1024);
    ln_kernel<<<NR, 256, 0, stream>>>(buf, g3, b3, out);
}

// Round 2
// 216.921 us; speedup vs baseline: 4.0764x; 4.0764x over previous
//
#include <hip/hip_runtime.h>
#include <hip/hip_bf16.h>

#define TT 2048

typedef __attribute__((ext_vector_type(4))) float f32x4;
typedef __attribute__((ext_vector_type(8))) __bf16 bf16x8;
typedef __attribute__((ext_vector_type(4))) short short4v;

enum { M_CONV = 0, M_QKV = 1, M_PROJ = 2, M_FFN1 = 3, M_FFN2 = 4 };

__device__ __forceinline__ void gload16(const void* g, void* l) {
    __builtin_amdgcn_global_load_lds(
        (__attribute__((address_space(1))) void*)g,
        (__attribute__((address_space(3))) void*)l, 16, 0, 0);
}

__device__ __forceinline__ short f2bf(float f) {
    unsigned u = __float_as_uint(f);
    u = (u + 0x7fffu + ((u >> 16) & 1u)) >> 16;
    return (short)u;
}

// ---------------------------------------------------------------------------
// Weight cast/transpose kernels (run every call; tiny)
// ---------------------------------------------------------------------------
// conv_w [O=512][I=512][K=3] -> cwT[o][tap*512+i] bf16  (Wt layout [N][K'])
__global__ void cast_convw(const float* __restrict__ src, short* __restrict__ dst) {
    int idx = blockIdx.x * 256 + threadIdx.x;      // < 3*512*512
    int tap = idx >> 18, i = (idx >> 9) & 511, o = idx & 511;
    dst[(size_t)o * 1536 + tap * 512 + i] = f2bf(src[((size_t)o * 512 + i) * 3 + tap]);
}

// src [K][N] f32 -> dst [N][K] bf16 ; K = 1<<kshift
__global__ void cast_wT(const float* __restrict__ src, short* __restrict__ dst,
                        int N, int kshift) {
    int idx = blockIdx.x * 256 + threadIdx.x;
    int n = idx >> kshift, k = idx & ((1 << kshift) - 1);
    dst[idx] = f2bf(src[(size_t)k * N + n]);
}

// x [2][2048][512] f32 -> xpad [2][2050][512] bf16 (2 leading zero rows/batch)
__global__ void cast_xpad(const float* __restrict__ x, short* __restrict__ xp) {
    int idx = blockIdx.x * 256 + threadIdx.x;      // < 2050*512
    int bb = blockIdx.y;
    int i = idx & 511, rp = idx >> 9;
    int t = rp - 2;
    float v = (t >= 0) ? x[((size_t)(bb << 11) + t) * 512 + i] : 0.f;
    xp[((size_t)bb * 2050 + rp) * 512 + i] = f2bf(v);
}

// ---------------------------------------------------------------------------
// Row LayerNorm over C=512: f32 in -> f32 out + optional bf16 out
// ---------------------------------------------------------------------------
__global__ __launch_bounds__(256) void ln2_kernel(const float* __restrict__ in,
                                                  const float* __restrict__ g,
                                                  const float* __restrict__ b,
                                                  float* __restrict__ outf,
                                                  short* __restrict__ outb) {
    int row = blockIdx.x;
    int tid = threadIdx.x;
    const float* p = in + (size_t)row * 512;
    float2 v = *(const float2*)(p + tid * 2);
    float s = v.x + v.y;
    float ss = v.x * v.x + v.y * v.y;
    #pragma unroll
    for (int off = 1; off < 64; off <<= 1) {
        s  += __shfl_xor(s, off);
        ss += __shfl_xor(ss, off);
    }
    __shared__ float sm[4], sm2[4];
    int w = tid >> 6;
    if ((tid & 63) == 0) { sm[w] = s; sm2[w] = ss; }
    __syncthreads();
    s  = sm[0] + sm[1] + sm[2] + sm[3];
    ss = sm2[0] + sm2[1] + sm2[2] + sm2[3];
    float mean = s * (1.f / 512);
    float var  = ss * (1.f / 512) - mean * mean;
    float rstd = rsqrtf(var + 1e-5f);
    float2 gg = *(const float2*)(g + tid * 2);
    float2 bb = *(const float2*)(b + tid * 2);
    float ox = (v.x - mean) * rstd * gg.x + bb.x;
    float oy = (v.y - mean) * rstd * gg.y + bb.y;
    *(float2*)(outf + (size_t)row * 512 + tid * 2) = make_float2(ox, oy);
    if (outb) {
        unsigned pk = ((unsigned)(unsigned short)f2bf(oy) << 16) |
                      (unsigned)(unsigned short)f2bf(ox);
        *(unsigned*)&outb[(size_t)row * 512 + tid * 2] = pk;
    }
}

// ---------------------------------------------------------------------------
// bf16 MFMA GEMM: C[4096][N] = A[4096][K] @ Wt[N][K]^T, m97-style staging.
// BM=128, BK=32, 256 threads = 4 waves (2x2), wave tile 64 x BN/2.
// ---------------------------------------------------------------------------
template<int MODE, int BN>
__global__ __launch_bounds__(256) void gemm_mfma(
    const short* __restrict__ A, const short* __restrict__ Bw,
    const float* __restrict__ bias, const float* __restrict__ res,
    void* __restrict__ Cout, short* __restrict__ vTb, int K) {
    constexpr int NF = BN / 32;
    constexpr int NOUT = (MODE == M_QKV) ? 1536 : (MODE == M_FFN1) ? 1024 : 512;
    __shared__ short As[128 * 32];
    __shared__ short Bs[BN * 32];
    const int tid = threadIdx.x;
    const int w = tid >> 6, l = tid & 63;
    const int wm = w >> 1, wn = w & 1;
    const int lr = l & 15, lc = l >> 4;
    const int m0 = blockIdx.y * 128, n0 = blockIdx.x * BN;
    f32x4 acc[4][NF];
    #pragma unroll
    for (int mf = 0; mf < 4; mf++)
        #pragma unroll
        for (int nf = 0; nf < NF; nf++) acc[mf][nf] = (f32x4){0.f, 0.f, 0.f, 0.f};

    for (int k0 = 0; k0 < K; k0 += 32) {
        #pragma unroll
        for (int i = 0; i < 2; i++) {
            int u = i * 256 + tid;
            int r = u >> 2, c = u & 3;
            const short* gp;
            if constexpr (MODE == M_CONV) {
                int row = m0 + r;
                int bb = row >> 11, t5 = row & 2047;
                int tap = k0 >> 9, kk = k0 & 511;
                gp = A + ((size_t)(bb * 2050 + t5 + tap) * 512 + kk + c * 8);
            } else {
                gp = A + ((size_t)(m0 + r) * K + k0 + c * 8);
            }
            gload16(gp, (char*)As + u * 16);
        }
        #pragma unroll
        for (int i = 0; i < BN / 64; i++) {
            int u = i * 256 + tid;
            int r = u >> 2, c = u & 3;
            gload16(Bw + ((size_t)(n0 + r) * K + k0 + c * 8), (char*)Bs + u * 16);
        }
        __syncthreads();
        bf16x8 af[4];
        #pragma unroll
        for (int mf = 0; mf < 4; mf++)
            af[mf] = *(const bf16x8*)&As[(wm * 64 + mf * 16 + lr) * 32 + lc * 8];
        #pragma unroll
        for (int nf = 0; nf < NF; nf++) {
            bf16x8 bfr = *(const bf16x8*)&Bs[(wn * (BN / 2) + nf * 16 + lr) * 32 + lc * 8];
            #pragma unroll
            for (int mf = 0; mf < 4; mf++)
                acc[mf][nf] = __builtin_amdgcn_mfma_f32_16x16x32_bf16(
                    af[mf], bfr, acc[mf][nf], 0, 0, 0);
        }
        __syncthreads();
    }
    // epilogue
    #pragma unroll
    for (int mf = 0; mf < 4; mf++) {
        int row0 = m0 + wm * 64 + mf * 16 + lc * 4;
        #pragma unroll
        for (int nf = 0; nf < NF; nf++) {
            int col = n0 + wn * (BN / 2) + nf * 16 + lr;
            float bv = bias[col];
            if constexpr (MODE == M_CONV || MODE == M_PROJ || MODE == M_FFN2) {
                float* Cf = (float*)Cout;
                #pragma unroll
                for (int rg = 0; rg < 4; rg++) {
                    size_t off = (size_t)(row0 + rg) * 512 + col;
                    Cf[off] = acc[mf][nf][rg] + bv + res[off];
                }
            } else if constexpr (MODE == M_FFN1) {
                short* Cb = (short*)Cout;
                #pragma unroll
                for (int rg = 0; rg < 4; rg++)
                    Cb[(size_t)(row0 + rg) * 1024 + col] =
                        f2bf(fmaxf(acc[mf][nf][rg] + bv, 0.f));
            } else {  // M_QKV
                short* Cb = (short*)Cout;
                float v[4];
                #pragma unroll
                for (int rg = 0; rg < 4; rg++) {
                    v[rg] = acc[mf][nf][rg] + bv;
                    Cb[(size_t)(row0 + rg) * 1536 + col] = f2bf(v[rg]);
                }
                if (col >= 1024) {  // also write V transposed: vT[bh][d][t]
                    int vc = col - 1024, hh = vc >> 6, dd = vc & 63;
                    int bb = row0 >> 11, t5 = row0 & 2047;
                    short4v pk = {f2bf(v[0]), f2bf(v[1]), f2bf(v[2]), f2bf(v[3])};
                    *(short4v*)&vTb[((size_t)((bb << 3) + hh) * 64 + dd) * 2048 + t5] = pk;
                }
            }
        }
    }
    (void)NOUT;
}

// ---------------------------------------------------------------------------
// bf16 MFMA flash attention. Q/K from qkvb [4096][1536], V from vT [16][64][2048].
// grid (16 pairs, 16 bh); block 256 = 4 waves; each block does Q-tiles {j, 31-j}
// (33 K-iters each => uniform load). LDS tiles [64][64] bf16 chunk-swizzled
// (c ^= r&7) on both staging-source and read side; P via padded LDS.
// ---------------------------------------------------------------------------
__global__ __launch_bounds__(256) void attn_mfma(const short* __restrict__ qkvb,
                                                 const short* __restrict__ vTb,
                                                 short* __restrict__ aout) {
    __shared__ short Qs[64 * 64];
    __shared__ short Ks[64 * 64];
    __shared__ short Vs[64 * 64];
    __shared__ short Ps[64 * 72];
    const int tid = threadIdx.x;
    const int w = tid >> 6, l = tid & 63;
    const int lr = l & 15, lc = l >> 4;
    const int pair = blockIdx.x, bh = blockIdx.y;
    const int b = bh >> 3, h = bh & 7;
    const int qr = w * 16;

    for (int half = 0; half < 2; half++) {
        const int qt = half ? (31 - pair) : pair;
        const int q0 = qt * 64;
        #pragma unroll
        for (int i = 0; i < 2; i++) {
            int u = i * 256 + tid;
            int r = u >> 3, c = (u & 7) ^ (r & 7);
            gload16(qkvb + ((size_t)(b * 2048 + q0 + r) * 1536 + h * 64 + c * 8),
                    (char*)Qs + u * 16);
        }
        f32x4 o[4];
        float mst[4], lst[4], alpha[4];
        #pragma unroll
        for (int nf = 0; nf < 4; nf++) o[nf] = (f32x4){0.f, 0.f, 0.f, 0.f};
        #pragma unroll
        for (int rg = 0; rg < 4; rg++) { mst[rg] = -1e30f; lst[rg] = 0.f; }

        for (int kt = 0; kt <= qt; kt++) {
            #pragma unroll
            for (int i = 0; i < 2; i++) {
                int u = i * 256 + tid;
                int r = u >> 3, c = (u & 7) ^ (r & 7);
                gload16(qkvb + ((size_t)(b * 2048 + kt * 64 + r) * 1536 + 512 + h * 64 + c * 8),
                        (char*)Ks + u * 16);
            }
            #pragma unroll
            for (int i = 0; i < 2; i++) {
                int u = i * 256 + tid;
                int r = u >> 3, c = (u & 7) ^ (r & 7);
                gload16(vTb + ((size_t)(bh * 64 + r) * 2048 + kt * 64 + c * 8),
                        (char*)Vs + u * 16);
            }
            __syncthreads();
            // S = Q @ K^T  (wave rows qr..qr+15, all 64 kv cols)
            f32x4 s[4];
            #pragma unroll
            for (int nf = 0; nf < 4; nf++) s[nf] = (f32x4){0.f, 0.f, 0.f, 0.f};
            bf16x8 aq[2];
            #pragma unroll
            for (int ks = 0; ks < 2; ks++) {
                int rr = qr + lr;
                int cc = (lc + 4 * ks) ^ (rr & 7);
                aq[ks] = *(const bf16x8*)&Qs[rr * 64 + cc * 8];
            }
            #pragma unroll
            for (int nf = 0; nf < 4; nf++) {
                #pragma unroll
                for (int ks = 0; ks < 2; ks++) {
                    int rr = nf * 16 + lr;
                    int cc = (lc + 4 * ks) ^ (rr & 7);
                    bf16x8 bk = *(const bf16x8*)&Ks[rr * 64 + cc * 8];
                    s[nf] = __builtin_amdgcn_mfma_f32_16x16x32_bf16(aq[ks], bk, s[nf], 0, 0, 0);
                }
            }
            // online softmax (rows: (lc*4+rg); cols within 16-lane groups)
            const bool diag = (kt == qt);
            #pragma unroll
            for (int rg = 0; rg < 4; rg++) {
                int row_g = q0 + qr + lc * 4 + rg;
                float v0 = s[0][rg] * 0.125f, v1 = s[1][rg] * 0.125f;
                float v2 = s[2][rg] * 0.125f, v3 = s[3][rg] * 0.125f;
                if (diag) {
                    int cb = kt * 64 + lr;
                    if (cb      > row_g) v0 = -1e30f;
                    if (cb + 16 > row_g) v1 = -1e30f;
                    if (cb + 32 > row_g) v2 = -1e30f;
                    if (cb + 48 > row_g) v3 = -1e30f;
                }
                float rm = fmaxf(fmaxf(v0, v1), fmaxf(v2, v3));
                rm = fmaxf(rm, __shfl_xor(rm, 1));
                rm = fmaxf(rm, __shfl_xor(rm, 2));
                rm = fmaxf(rm, __shfl_xor(rm, 4));
                rm = fmaxf(rm, __shfl_xor(rm, 8));
                float mn = fmaxf(mst[rg], rm);
                alpha[rg] = __expf(mst[rg] - mn);
                mst[rg] = mn;
                float p0 = __expf(v0 - mn), p1 = __expf(v1 - mn);
                float p2 = __expf(v2 - mn), p3 = __expf(v3 - mn);
                int prow = (qr + lc * 4 + rg) * 72;
                Ps[prow      + lr] = f2bf(p0);
                Ps[prow + 16 + lr] = f2bf(p1);
                Ps[prow + 32 + lr] = f2bf(p2);
                Ps[prow + 48 + lr] = f2bf(p3);
                float rs = p0 + p1 + p2 + p3;
                rs += __shfl_xor(rs, 1);
                rs += __shfl_xor(rs, 2);
                rs += __shfl_xor(rs, 4);
                rs += __shfl_xor(rs, 8);
                lst[rg] = lst[rg] * alpha[rg] + rs;
            }
            #pragma unroll
            for (int nf = 0; nf < 4; nf++)
                #pragma unroll
                for (int rg = 0; rg < 4; rg++) o[nf][rg] *= alpha[rg];
            // O += P @ V   (P rows wave-local in Ps; V as Vs[d][kv])
            bf16x8 pa[2];
            #pragma unroll
            for (int ks = 0; ks < 2; ks++)
                pa[ks] = *(const bf16x8*)&Ps[(qr + lr) * 72 + ks * 32 + lc * 8];
            #pragma unroll
            for (int nf = 0; nf < 4; nf++) {
                #pragma unroll
                for (int ks = 0; ks < 2; ks++) {
                    int rr = nf * 16 + lr;
                    int cc = (lc + 4 * ks) ^ (rr & 7);
                    bf16x8 bv = *(const bf16x8*)&Vs[rr * 64 + cc * 8];
                    o[nf] = __builtin_amdgcn_mfma_f32_16x16x32_bf16(pa[ks], bv, o[nf], 0, 0, 0);
                }
            }
            __syncthreads();
        }
        #pragma unroll
        for (int nf = 0; nf < 4; nf++) {
            #pragma unroll
            for (int rg = 0; rg < 4; rg++) {
                float ov = o[nf][rg] / lst[rg];
                aout[(size_t)(b * 2048 + q0 + qr + lc * 4 + rg) * 512 + h * 64 + nf * 16 + lr] =
                    f2bf(ov);
            }
        }
    }
}

// ---------------------------------------------------------------------------
extern "C" void kernel_launch(void* const* d_in, const int* in_sizes, int n_in,
                              void* d_out, int out_size, void* d_ws, size_t ws_size,
                              hipStream_t stream) {
    const float* x      = (const float*)d_in[0];
    const float* conv_w = (const float*)d_in[1];
    const float* conv_b = (const float*)d_in[2];
    const float* g1     = (const float*)d_in[3];
    const float* b1     = (const float*)d_in[4];
    const float* qkv_w  = (const float*)d_in[5];
    const float* qkv_b  = (const float*)d_in[6];
    const float* proj_w = (const float*)d_in[7];
    const float* proj_b = (const float*)d_in[8];
    const float* g2     = (const float*)d_in[9];
    const float* b2     = (const float*)d_in[10];
    const float* ffn_w1 = (const float*)d_in[11];
    const float* ffn_b1 = (const float*)d_in[12];
    const float* ffn_w2 = (const float*)d_in[13];
    const float* ffn_b2 = (const float*)d_in[14];
    const float* g3     = (const float*)d_in[15];
    const float* b3     = (const float*)d_in[16];
    float* out = (float*)d_out;

    char* p = (char*)d_ws;
    short* cwT   = (short*)p;  p += 786432 * 2;
    short* qkvT  = (short*)p;  p += 786432 * 2;
    short* projT = (short*)p;  p += 262144 * 2;
    short* f1T   = (short*)p;  p += 524288 * 2;
    short* f2T   = (short*)p;  p += 524288 * 2;
    short* xpad  = (short*)p;  p += 2099200 * 2;
    float* yb    = (float*)p;  p += 2097152 * 4;
    float* x1f   = (float*)p;  p += 2097152 * 4;
    short* x1b   = (short*)p;  p += 2097152 * 2;
    short* qkvb  = (short*)p;  p += 6291456 * 2;
    short* vTb   = (short*)p;  p += 2097152 * 2;
    // aliases of dead buffers:
    float* x2f     = x1f;   // x1f dead after proj epilogue
    short* x2b     = x1b;   // x1b dead after qkv GEMM
    short* attnout = xpad;  // xpad dead after conv GEMM
    short* hb      = qkvb;  // qkvb dead after attention

    cast_convw<<<3072, 256, 0, stream>>>(conv_w, cwT);
    cast_wT<<<3072, 256, 0, stream>>>(qkv_w, qkvT, 1536, 9);
    cast_wT<<<1024, 256, 0, stream>>>(proj_w, projT, 512, 9);
    cast_wT<<<2048, 256, 0, stream>>>(ffn_w1, f1T, 1024, 9);
    cast_wT<<<2048, 256, 0, stream>>>(ffn_w2, f2T, 512, 10);
    cast_xpad<<<dim3(4100, 2), 256, 0, stream>>>(x, xpad);

    gemm_mfma<M_CONV, 64><<<dim3(8, 32), 256, 0, stream>>>(
        xpad, cwT, conv_b, x, yb, nullptr, 1536);
    ln2_kernel<<<4096, 256, 0, stream>>>(yb, g1, b1, x1f, x1b);
    gemm_mfma<M_QKV, 128><<<dim3(12, 32), 256, 0, stream>>>(
        x1b, qkvT, qkv_b, nullptr, qkvb, vTb, 512);
    attn_mfma<<<dim3(16, 16), 256, 0, stream>>>(qkvb, vTb, attnout);
    gemm_mfma<M_PROJ, 64><<<dim3(8, 32), 256, 0, stream>>>(
        attnout, projT, proj_b, x1f, yb, nullptr, 512);
    ln2_kernel<<<4096, 256, 0, stream>>>(yb, g2, b2, x2f, x2b);
    gemm_mfma<M_FFN1, 128><<<dim3(8, 32), 256, 0, stream>>>(
        x2b, f1T, ffn_b1, nullptr, hb, nullptr, 512);
    gemm_mfma<M_FFN2, 64><<<dim3(8, 32), 256, 0, stream>>>(
        hb, f2T, ffn_b2, x2f, yb, nullptr, 1024);
    ln2_kernel<<<4096, 256, 0, stream>>>(yb, g3, b3, out, nullptr);
}